// Round 11
// baseline (564.469 us; speedup 1.0000x reference)
//
#include <hip/hip_runtime.h>
#include <hip/hip_fp16.h>
#include <math.h>

#define FIN 512
#define H   64
#define C   20
#define CP  32     // padded layer-2 row: 32 halves = 64B, one cache line
#define SLOT 64    // fixed edata slots per node (P(deg>64) ~ e^-12 per node)
#define OVFCAP 4096

typedef _Float16 half8 __attribute__((ext_vector_type(8)));
typedef float floatx4 __attribute__((ext_vector_type(4)));

// ---------------- inline edge-index layout detection -------------------------
__device__ __forceinline__ int detect_m64(const int* __restrict__ ei) {
    int nz = 0;
    #pragma unroll
    for (int i = 0; i < 32; i++) nz |= ei[2 * i + 1];
    return nz == 0;   // 1 => int64 layout
}

__device__ __forceinline__ int edge_val(const int* __restrict__ ei, long long idx, int m64) {
    return m64 ? ei[2 * idx] : ei[(int)idx];
}

// ---------------- init: W1 transpose+cast AND packed=0 (one launch) ----------
__global__ void init_kernel(const float* __restrict__ W, _Float16* __restrict__ W1T,
                            unsigned long long* __restrict__ packed, int* __restrict__ ovfcnt,
                            int N) {
    int tid = blockIdx.x * 256 + threadIdx.x;
    if (tid < H * FIN) {               // 32768: W1T[n][k] = (f16)W1[k][n]
        int n = tid >> 9, k = tid & 511;
        W1T[tid] = (_Float16)W[k * H + n];
    }
    if (tid < N) packed[tid] = 0ULL;
    if (tid == 0) *ovfcnt = 0;
}

// ---------------- fused: gemm1 (MFMA) + hist+direct-scatter, interleaved -----
// Fixed-stride edata layout (node d owns slots [d*64, d*64+64)): hist role
// scatters {src, ew} DIRECTLY at rank position; scatter RMW traffic hides
// under the atomic-latency floor. packed[d]: count<<40 | fixpoint ew-sum.
#define FIXSCALE 268435456.0f   // 2^28
#define KC 64
#define GM 64                   // gemm rows per block
#define HE 2048                 // hist edges per block (8 per thread)
__global__ __launch_bounds__(256, 8) void fused_gemm1_hist_kernel(
        const float* __restrict__ x, const _Float16* __restrict__ W1T,
        float* __restrict__ xw1f, int N,
        const int* __restrict__ ei, const float* __restrict__ ew,
        unsigned long long* __restrict__ packed, int2* __restrict__ edata,
        int* __restrict__ ovfcnt, int4* __restrict__ ovf,
        int E, int GB, int HB) {
    __shared__ _Float16 xsh[GM][72];    // [row][k] stride 144B: 16B-divisible, non-2^k
    __shared__ _Float16 wsh[64][72];    // [n][k]

    // ---- role decode: even -> hist, odd -> gemm while both remain ----------
    int nb = blockIdx.x;
    int minB = (GB < HB) ? GB : HB;
    int isHist, roleId;
    if (nb < 2 * minB) { isHist = !(nb & 1); roleId = nb >> 1; }
    else { int r = nb - 2 * minB; isHist = (HB > GB); roleId = minB + r; }

    if (isHist) {
        // ---- histrank role: 8 edges/thread, atomic + direct edata scatter ---
        int m64 = detect_m64(ei);
        long long base = (long long)roleId * HE + threadIdx.x;
        int d[8], s[8]; float w[8];
        #pragma unroll
        for (int u = 0; u < 8; u++) {
            long long e = base + u * 256;
            if (e < E) {
                d[u] = edge_val(ei, (long long)E + e, m64);
                s[u] = edge_val(ei, e, m64);
                w[u] = ew[e];
            } else d[u] = -1;
        }
        unsigned long long old[8];
        #pragma unroll
        for (int u = 0; u < 8; u++)
            if (d[u] >= 0) {
                unsigned long long add = (1ULL << 40) |
                    (unsigned long long)(w[u] * FIXSCALE + 0.5f);
                old[u] = atomicAdd(&packed[d[u]], add);
            }
        #pragma unroll
        for (int u = 0; u < 8; u++)
            if (d[u] >= 0) {
                int rk = (int)(old[u] >> 40);
                if (rk < SLOT)
                    edata[d[u] * SLOT + rk] = make_int2(s[u], __float_as_int(w[u]));
                else {
                    int oi = atomicAdd(ovfcnt, 1);
                    if (oi < OVFCAP) ovf[oi] = make_int4(d[u], s[u], __float_as_int(w[u]), 0);
                }
            }
        return;
    }

    // ---------------------- GEMM1 role: 64x64 tile, KC=64 -------------------
    int tid  = threadIdx.x;
    int wave = tid >> 6;
    int lane = tid & 63;
    int quad = lane >> 4;
    int l16  = lane & 15;
    int row0 = roleId * GM;

    floatx4 acc[4];
    #pragma unroll
    for (int ct = 0; ct < 4; ct++) acc[ct] = (floatx4){0.f, 0.f, 0.f, 0.f};

    int col4  = (tid & 15) * 4;   // x staging: k offset (16 thr/row x 4 floats = 64 k)
    int rbase = tid >> 4;         // x staging: row base (0..15), 4 passes of 16 rows
    int wn = tid >> 2;            // W staging: n (4 thr/row)
    int wk = (tid & 3) * 16;      // W staging: k offset; 2x half8 = 16 k each

    for (int k0 = 0; k0 < FIN; k0 += KC) {
        #pragma unroll
        for (int it = 0; it < 4; it++) {
            int row = rbase + it * 16;
            int grow = row0 + row; if (grow >= N) grow = N - 1;
            float4 v = *(const float4*)&x[(long long)grow * FIN + k0 + col4];
            _Float16* p = &xsh[row][col4];
            p[0] = (_Float16)v.x; p[1] = (_Float16)v.y;
            p[2] = (_Float16)v.z; p[3] = (_Float16)v.w;
        }
        *(half8*)&wsh[wn][wk]     = *(const half8*)&W1T[wn * FIN + k0 + wk];
        *(half8*)&wsh[wn][wk + 8] = *(const half8*)&W1T[wn * FIN + k0 + wk + 8];
        __syncthreads();
        #pragma unroll
        for (int kk = 0; kk < KC; kk += 32) {
            half8 a0 = *(const half8*)&xsh[wave * 16 + l16][kk + quad * 8];
            #pragma unroll
            for (int ct = 0; ct < 4; ct++) {
                half8 b = *(const half8*)&wsh[ct * 16 + l16][kk + quad * 8];
                acc[ct] = __builtin_amdgcn_mfma_f32_16x16x32_f16(a0, b, acc[ct], 0, 0, 0);
            }
        }
        __syncthreads();
    }
    #pragma unroll
    for (int ct = 0; ct < 4; ct++)
        #pragma unroll
        for (int r = 0; r < 4; r++) {
            int grow = row0 + wave * 16 + quad * 4 + r;
            if (grow < N)
                xw1f[(long long)grow * H + ct * 16 + l16] = acc[ct][r];
        }
}

// ---------------- dinv + scale: xws = (f16)(dinv * xw1f), dinv from packed ---
__global__ void dinvscale_kernel(const unsigned long long* __restrict__ packed,
                                 const float* __restrict__ xw1f,
                                 float* __restrict__ dinv, _Float16* __restrict__ xws, int N) {
    long long t = (long long)blockIdx.x * 256 + threadIdx.x;
    if (t >= (long long)N * 8) return;
    int i  = (int)(t >> 3);
    int fo = ((int)t & 7) * 8;
    unsigned long long v = packed[i];
    float di = rsqrtf((float)(v & ((1ULL << 40) - 1)) * (1.0f / FIXSCALE) + 1.0f);
    if (((int)t & 7) == 0) dinv[i] = di;
    const float4* p = (const float4*)&xw1f[(long long)i * H + fo];
    float4 v0 = p[0], v1 = p[1];
    half8 o;
    o[0] = (_Float16)(v0.x * di); o[1] = (_Float16)(v0.y * di);
    o[2] = (_Float16)(v0.z * di); o[3] = (_Float16)(v0.w * di);
    o[4] = (_Float16)(v1.x * di); o[5] = (_Float16)(v1.y * di);
    o[6] = (_Float16)(v1.z * di); o[7] = (_Float16)(v1.w * di);
    *(half8*)&xws[(long long)i * H + fo] = o;
}

// ------- agg layer 1 + relu + gemm2 fused: 8 nodes/wave, 8 lanes/node --------
// lane q in [0,8) holds features 8q..8q+7 (one 16B uint4 load = full 128B row
// per 8-lane group). start = i*SLOT, cnt from packed (no rowptr).
#define A1_NODES 32
__global__ __launch_bounds__(256) void agg1g2_kernel(
        const unsigned long long* __restrict__ packed, const int2* __restrict__ edata,
        const _Float16* __restrict__ xws, const float* __restrict__ dinv,
        const float* __restrict__ b1, const float* __restrict__ W2,
        const int* __restrict__ ovfcnt, const int4* __restrict__ ovf,
        __half* __restrict__ zp, int N) {
    __shared__ float hs[A1_NODES][H + 2];   // 32x66x4 = 8.4KB
    __shared__ float w2s[H * C];            // 5KB
    for (int t = threadIdx.x; t < H * C; t += 256) w2s[t] = W2[t];
    __syncthreads();                        // ONLY barrier (w2s visibility)

    const __half* xh = (const __half*)xws;
    int wv = threadIdx.x >> 6;              // wave 0..3
    int l  = threadIdx.x & 63;
    int g  = l >> 3;                        // node group 0..7 within wave
    int q  = l & 7;                         // sublane: features 8q..8q+7
    int slot = wv * 8 + g;
    int i  = blockIdx.x * A1_NODES + slot;
    if (i < N) {
        int start = i * SLOT;
        int cnt = (int)(packed[i] >> 40);
        if (cnt > SLOT) cnt = SLOT;         // overflow handled via list below
        int end = start + cnt;
        float a0=0.f,a1=0.f,a2=0.f,a3=0.f,a4=0.f,a5=0.f,a6=0.f,a7=0.f;
        int j = start;
        for (; j + 3 < end; j += 4) {
            int2 e0 = edata[j], e1 = edata[j + 1], e2 = edata[j + 2], e3 = edata[j + 3];
            uint4 u0 = *(const uint4*)&xh[(long long)e0.x * H + 8 * q];
            uint4 u1 = *(const uint4*)&xh[(long long)e1.x * H + 8 * q];
            uint4 u2 = *(const uint4*)&xh[(long long)e2.x * H + 8 * q];
            uint4 u3 = *(const uint4*)&xh[(long long)e3.x * H + 8 * q];
            float n0 = __int_as_float(e0.y), n1 = __int_as_float(e1.y);
            float n2 = __int_as_float(e2.y), n3 = __int_as_float(e3.y);
            float2 p;
            p = __half22float2(*(const __half2*)&u0.x); a0=fmaf(p.x,n0,a0); a1=fmaf(p.y,n0,a1);
            p = __half22float2(*(const __half2*)&u0.y); a2=fmaf(p.x,n0,a2); a3=fmaf(p.y,n0,a3);
            p = __half22float2(*(const __half2*)&u0.z); a4=fmaf(p.x,n0,a4); a5=fmaf(p.y,n0,a5);
            p = __half22float2(*(const __half2*)&u0.w); a6=fmaf(p.x,n0,a6); a7=fmaf(p.y,n0,a7);
            p = __half22float2(*(const __half2*)&u1.x); a0=fmaf(p.x,n1,a0); a1=fmaf(p.y,n1,a1);
            p = __half22float2(*(const __half2*)&u1.y); a2=fmaf(p.x,n1,a2); a3=fmaf(p.y,n1,a3);
            p = __half22float2(*(const __half2*)&u1.z); a4=fmaf(p.x,n1,a4); a5=fmaf(p.y,n1,a5);
            p = __half22float2(*(const __half2*)&u1.w); a6=fmaf(p.x,n1,a6); a7=fmaf(p.y,n1,a7);
            p = __half22float2(*(const __half2*)&u2.x); a0=fmaf(p.x,n2,a0); a1=fmaf(p.y,n2,a1);
            p = __half22float2(*(const __half2*)&u2.y); a2=fmaf(p.x,n2,a2); a3=fmaf(p.y,n2,a3);
            p = __half22float2(*(const __half2*)&u2.z); a4=fmaf(p.x,n2,a4); a5=fmaf(p.y,n2,a5);
            p = __half22float2(*(const __half2*)&u2.w); a6=fmaf(p.x,n2,a6); a7=fmaf(p.y,n2,a7);
            p = __half22float2(*(const __half2*)&u3.x); a0=fmaf(p.x,n3,a0); a1=fmaf(p.y,n3,a1);
            p = __half22float2(*(const __half2*)&u3.y); a2=fmaf(p.x,n3,a2); a3=fmaf(p.y,n3,a3);
            p = __half22float2(*(const __half2*)&u3.z); a4=fmaf(p.x,n3,a4); a5=fmaf(p.y,n3,a5);
            p = __half22float2(*(const __half2*)&u3.w); a6=fmaf(p.x,n3,a6); a7=fmaf(p.y,n3,a7);
        }
        for (; j < end; j++) {
            int2 e0 = edata[j];
            uint4 u0 = *(const uint4*)&xh[(long long)e0.x * H + 8 * q];
            float n0 = __int_as_float(e0.y);
            float2 p;
            p = __half22float2(*(const __half2*)&u0.x); a0=fmaf(p.x,n0,a0); a1=fmaf(p.y,n0,a1);
            p = __half22float2(*(const __half2*)&u0.y); a2=fmaf(p.x,n0,a2); a3=fmaf(p.y,n0,a3);
            p = __half22float2(*(const __half2*)&u0.z); a4=fmaf(p.x,n0,a4); a5=fmaf(p.y,n0,a5);
            p = __half22float2(*(const __half2*)&u0.w); a6=fmaf(p.x,n0,a6); a7=fmaf(p.y,n0,a7);
        }
        // overflow edges (rank >= SLOT): ~never for Poisson(32)
        int nov = *ovfcnt;
        if (nov > 0) {
            nov = min(nov, OVFCAP);
            for (int k2 = 0; k2 < nov; k2++) {
                int4 o = ovf[k2];
                if (o.x == i) {
                    uint4 u0 = *(const uint4*)&xh[(long long)o.y * H + 8 * q];
                    float n0 = __int_as_float(o.z);
                    float2 p;
                    p = __half22float2(*(const __half2*)&u0.x); a0=fmaf(p.x,n0,a0); a1=fmaf(p.y,n0,a1);
                    p = __half22float2(*(const __half2*)&u0.y); a2=fmaf(p.x,n0,a2); a3=fmaf(p.y,n0,a3);
                    p = __half22float2(*(const __half2*)&u0.z); a4=fmaf(p.x,n0,a4); a5=fmaf(p.y,n0,a5);
                    p = __half22float2(*(const __half2*)&u0.w); a6=fmaf(p.x,n0,a6); a7=fmaf(p.y,n0,a7);
                }
            }
        }
        // self-loop: xws[i] already = dinv[i]*xw[i]
        uint4 us = *(const uint4*)&xh[(long long)i * H + 8 * q];
        float2 p;
        p = __half22float2(*(const __half2*)&us.x); a0 += p.x; a1 += p.y;
        p = __half22float2(*(const __half2*)&us.y); a2 += p.x; a3 += p.y;
        p = __half22float2(*(const __half2*)&us.z); a4 += p.x; a5 += p.y;
        p = __half22float2(*(const __half2*)&us.w); a6 += p.x; a7 += p.y;
        float di = dinv[i];
        float4 bb0 = *(const float4*)&b1[8 * q];
        float4 bb1 = *(const float4*)&b1[8 * q + 4];
        hs[slot][8 * q]     = fmaxf(fmaf(a0, di, bb0.x), 0.f);
        hs[slot][8 * q + 1] = fmaxf(fmaf(a1, di, bb0.y), 0.f);
        hs[slot][8 * q + 2] = fmaxf(fmaf(a2, di, bb0.z), 0.f);
        hs[slot][8 * q + 3] = fmaxf(fmaf(a3, di, bb0.w), 0.f);
        hs[slot][8 * q + 4] = fmaxf(fmaf(a4, di, bb1.x), 0.f);
        hs[slot][8 * q + 5] = fmaxf(fmaf(a5, di, bb1.y), 0.f);
        hs[slot][8 * q + 6] = fmaxf(fmaf(a6, di, bb1.z), 0.f);
        hs[slot][8 * q + 7] = fmaxf(fmaf(a7, di, bb1.w), 0.f);
    }
    // wave-synchronous epilogue: 4 passes x (2 nodes x 32 cols) = the wave's 8 nodes
    #pragma unroll
    for (int pass = 0; pass < 4; pass++) {
        int ns = wv * 8 + pass * 2 + (l >> 5);
        int c  = l & 31;
        int node = blockIdx.x * A1_NODES + ns;
        if (node < N) {
            float v = 0.f;
            if (c < C) {
                float acc = 0.f;
                #pragma unroll
                for (int k = 0; k < H; k++) acc = fmaf(hs[ns][k], w2s[k * C + c], acc);
                v = acc * dinv[node];      // z = dinv * (h @ W2)
            }
            zp[(long long)node * CP + c] = __float2half(v);   // full 64B line per node
        }
    }
}

// ------- agg layer 2 + softmax: 16 nodes/wave, 4 lanes/node ------------------
// R11 lever: lane q in [0,4) holds cols 8q..8q+7 (one 16B uint4 load; 4 lanes
// x 16B = full 64B padded row). Wave-iters = N/16 x E[max16]/4 ~= 0.6x R10's.
// Softmax over width-4 groups; q=2 half-valid (cols 16..19), q=3 pad-only.
__global__ void agg2_final_kernel(const unsigned long long* __restrict__ packed,
                                  const int2* __restrict__ edata,
                                  const __half* __restrict__ zp, const float* __restrict__ dinv,
                                  const float* __restrict__ b2,
                                  const int* __restrict__ ovfcnt, const int4* __restrict__ ovf,
                                  float* __restrict__ out, int N) {
    long long gid = (long long)blockIdx.x * blockDim.x + threadIdx.x;
    int wid = (int)(gid >> 6);
    int g = (threadIdx.x & 63) >> 2;   // node group 0..15
    int q = threadIdx.x & 3;           // cols 8q..8q+7
    int i = wid * 16 + g;
    float a0=0.f,a1=0.f,a2=0.f,a3=0.f,a4=0.f,a5=0.f,a6=0.f,a7=0.f;
    bool active = (i < N) && (q < 3);
    if (i < N) {
        int start = i * SLOT;
        int cnt = (int)(packed[i] >> 40);
        if (cnt > SLOT) cnt = SLOT;
        int end = start + cnt;
        int j = start;
        for (; j + 3 < end; j += 4) {
            int2 e0 = edata[j], e1 = edata[j + 1], e2 = edata[j + 2], e3 = edata[j + 3];
            uint4 u0 = *(const uint4*)&zp[(long long)e0.x * CP + 8 * q];
            uint4 u1 = *(const uint4*)&zp[(long long)e1.x * CP + 8 * q];
            uint4 u2 = *(const uint4*)&zp[(long long)e2.x * CP + 8 * q];
            uint4 u3 = *(const uint4*)&zp[(long long)e3.x * CP + 8 * q];
            float n0 = __int_as_float(e0.y), n1 = __int_as_float(e1.y);
            float n2 = __int_as_float(e2.y), n3 = __int_as_float(e3.y);
            float2 p;
            p = __half22float2(*(const __half2*)&u0.x); a0=fmaf(p.x,n0,a0); a1=fmaf(p.y,n0,a1);
            p = __half22float2(*(const __half2*)&u0.y); a2=fmaf(p.x,n0,a2); a3=fmaf(p.y,n0,a3);
            p = __half22float2(*(const __half2*)&u0.z); a4=fmaf(p.x,n0,a4); a5=fmaf(p.y,n0,a5);
            p = __half22float2(*(const __half2*)&u0.w); a6=fmaf(p.x,n0,a6); a7=fmaf(p.y,n0,a7);
            p = __half22float2(*(const __half2*)&u1.x); a0=fmaf(p.x,n1,a0); a1=fmaf(p.y,n1,a1);
            p = __half22float2(*(const __half2*)&u1.y); a2=fmaf(p.x,n1,a2); a3=fmaf(p.y,n1,a3);
            p = __half22float2(*(const __half2*)&u1.z); a4=fmaf(p.x,n1,a4); a5=fmaf(p.y,n1,a5);
            p = __half22float2(*(const __half2*)&u1.w); a6=fmaf(p.x,n1,a6); a7=fmaf(p.y,n1,a7);
            p = __half22float2(*(const __half2*)&u2.x); a0=fmaf(p.x,n2,a0); a1=fmaf(p.y,n2,a1);
            p = __half22float2(*(const __half2*)&u2.y); a2=fmaf(p.x,n2,a2); a3=fmaf(p.y,n2,a3);
            p = __half22float2(*(const __half2*)&u2.z); a4=fmaf(p.x,n2,a4); a5=fmaf(p.y,n2,a5);
            p = __half22float2(*(const __half2*)&u2.w); a6=fmaf(p.x,n2,a6); a7=fmaf(p.y,n2,a7);
            p = __half22float2(*(const __half2*)&u3.x); a0=fmaf(p.x,n3,a0); a1=fmaf(p.y,n3,a1);
            p = __half22float2(*(const __half2*)&u3.y); a2=fmaf(p.x,n3,a2); a3=fmaf(p.y,n3,a3);
            p = __half22float2(*(const __half2*)&u3.z); a4=fmaf(p.x,n3,a4); a5=fmaf(p.y,n3,a5);
            p = __half22float2(*(const __half2*)&u3.w); a6=fmaf(p.x,n3,a6); a7=fmaf(p.y,n3,a7);
        }
        for (; j < end; j++) {
            int2 e = edata[j];
            uint4 u = *(const uint4*)&zp[(long long)e.x * CP + 8 * q];
            float n = __int_as_float(e.y);
            float2 p;
            p = __half22float2(*(const __half2*)&u.x); a0=fmaf(p.x,n,a0); a1=fmaf(p.y,n,a1);
            p = __half22float2(*(const __half2*)&u.y); a2=fmaf(p.x,n,a2); a3=fmaf(p.y,n,a3);
            p = __half22float2(*(const __half2*)&u.z); a4=fmaf(p.x,n,a4); a5=fmaf(p.y,n,a5);
            p = __half22float2(*(const __half2*)&u.w); a6=fmaf(p.x,n,a6); a7=fmaf(p.y,n,a7);
        }
        int nov = *ovfcnt;
        if (nov > 0) {
            nov = min(nov, OVFCAP);
            for (int k2 = 0; k2 < nov; k2++) {
                int4 o = ovf[k2];
                if (o.x == i) {
                    uint4 u = *(const uint4*)&zp[(long long)o.y * CP + 8 * q];
                    float n = __int_as_float(o.z);
                    float2 p;
                    p = __half22float2(*(const __half2*)&u.x); a0=fmaf(p.x,n,a0); a1=fmaf(p.y,n,a1);
                    p = __half22float2(*(const __half2*)&u.y); a2=fmaf(p.x,n,a2); a3=fmaf(p.y,n,a3);
                    p = __half22float2(*(const __half2*)&u.z); a4=fmaf(p.x,n,a4); a5=fmaf(p.y,n,a5);
                    p = __half22float2(*(const __half2*)&u.w); a6=fmaf(p.x,n,a6); a7=fmaf(p.y,n,a7);
                }
            }
        }
        uint4 us = *(const uint4*)&zp[(long long)i * CP + 8 * q];
        float2 ps;
        ps = __half22float2(*(const __half2*)&us.x); a0 += ps.x; a1 += ps.y;  // self-loop
        ps = __half22float2(*(const __half2*)&us.y); a2 += ps.x; a3 += ps.y;
        ps = __half22float2(*(const __half2*)&us.z); a4 += ps.x; a5 += ps.y;
        ps = __half22float2(*(const __half2*)&us.w); a6 += ps.x; a7 += ps.y;
        float di = dinv[i];
        float4 bbA = make_float4(0.f,0.f,0.f,0.f), bbB = make_float4(0.f,0.f,0.f,0.f);
        if (q < 2) { bbA = *(const float4*)&b2[8 * q]; bbB = *(const float4*)&b2[8 * q + 4]; }
        else if (q == 2) { bbA = *(const float4*)&b2[16]; }
        a0 = fmaf(a0, di, bbA.x); a1 = fmaf(a1, di, bbA.y);
        a2 = fmaf(a2, di, bbA.z); a3 = fmaf(a3, di, bbA.w);
        a4 = fmaf(a4, di, bbB.x); a5 = fmaf(a5, di, bbB.y);
        a6 = fmaf(a6, di, bbB.z); a7 = fmaf(a7, di, bbB.w);
    }
    // validity: q<2 -> 8 cols, q==2 -> 4 cols (16..19), q==3 -> none
    int nvalid = active ? ((q == 2) ? 4 : 8) : 0;
    float mx = -1e30f;
    if (nvalid > 0) { mx = fmaxf(fmaxf(a0, a1), fmaxf(a2, a3));
        if (nvalid == 8) mx = fmaxf(mx, fmaxf(fmaxf(a4, a5), fmaxf(a6, a7))); }
    #pragma unroll
    for (int off = 2; off >= 1; off >>= 1) mx = fmaxf(mx, __shfl_xor(mx, off, 4));
    float e0_ = (nvalid > 0) ? expf(a0 - mx) : 0.f;
    float e1_ = (nvalid > 0) ? expf(a1 - mx) : 0.f;
    float e2_ = (nvalid > 0) ? expf(a2 - mx) : 0.f;
    float e3_ = (nvalid > 0) ? expf(a3 - mx) : 0.f;
    float e4_ = (nvalid == 8) ? expf(a4 - mx) : 0.f;
    float e5_ = (nvalid == 8) ? expf(a5 - mx) : 0.f;
    float e6_ = (nvalid == 8) ? expf(a6 - mx) : 0.f;
    float e7_ = (nvalid == 8) ? expf(a7 - mx) : 0.f;
    float sm = e0_ + e1_ + e2_ + e3_ + e4_ + e5_ + e6_ + e7_;
    #pragma unroll
    for (int off = 2; off >= 1; off >>= 1) sm += __shfl_xor(sm, off, 4);
    if (nvalid > 0) {
        float inv = 1.f / sm;
        *(float4*)&out[(long long)i * C + 8 * q] = make_float4(e0_*inv, e1_*inv, e2_*inv, e3_*inv);
        if (nvalid == 8)
            *(float4*)&out[(long long)i * C + 8 * q + 4] = make_float4(e4_*inv, e5_*inv, e6_*inv, e7_*inv);
    }
}

// ---------------- launch -----------------------------------------------------
static inline size_t align256(size_t x) { return (x + 255) & ~(size_t)255; }

extern "C" void kernel_launch(void* const* d_in, const int* in_sizes, int n_in,
                              void* d_out, int out_size, void* d_ws, size_t ws_size,
                              hipStream_t stream) {
    const float* x  = (const float*)d_in[0];
    const int*   ei = (const int*)d_in[1];
    const float* ew = (const float*)d_in[2];
    const float* W1 = (const float*)d_in[3];
    const float* b1 = (const float*)d_in[4];
    const float* W2 = (const float*)d_in[5];
    const float* b2 = (const float*)d_in[6];
    float* out = (float*)d_out;

    int N = in_sizes[0] / FIN;   // 100000
    int E = in_sizes[2];         // 3200000

    char* ws = (char*)d_ws;
    size_t off = 0;
    unsigned long long* packed = (unsigned long long*)(ws + off); off = align256(off + (size_t)N * 8);
    float*    dinv    = (float*)(ws + off);    off = align256(off + (size_t)N * 4);
    int2*     edata   = (int2*)(ws + off);     off = align256(off + (size_t)N * SLOT * 8);  // 51.2MB
    _Float16* W1T     = (_Float16*)(ws + off); off = align256(off + (size_t)H * FIN * 2);
    // xw1f (fp32, gemm->dinvscale) then reused as zp (agg1g2->agg2): 6.4MB <= 25.6MB
    float*  xw1f = (float*)(ws + off);
    __half* zp   = (__half*)(ws + off);        off = align256(off + (size_t)N * H * 4);
    _Float16* xws     = (_Float16*)(ws + off); off = align256(off + (size_t)N * H * 2);
    int*      ovfcnt  = (int*)(ws + off);      off = align256(off + 256);
    int4*     ovf     = (int4*)(ws + off);     off = align256(off + (size_t)OVFCAP * 16);

    // init: W1T transpose + packed=0 + ovfcnt=0
    int initBlocks = (max(H * FIN, N) + 255) / 256;
    init_kernel<<<initBlocks, 256, 0, stream>>>(W1, W1T, packed, ovfcnt, N);

    // Fused: parity-interleaved hist (even) / gemm (odd) blocks.
    int GB = (N + GM - 1) / GM;          // 1563
    int HB = (E + HE - 1) / HE;          // 1563
    fused_gemm1_hist_kernel<<<GB + HB, 256, 0, stream>>>(
        x, W1T, xw1f, N, ei, ew, packed, edata, ovfcnt, ovf, E, GB, HB);

    // dinv + scale (xw1f dies here; zp may overlay it afterwards)
    dinvscale_kernel<<<(int)(((long long)N * 8 + 255) / 256), 256, 0, stream>>>(
        packed, xw1f, dinv, xws, N);

    agg1g2_kernel<<<(N + A1_NODES - 1) / A1_NODES, 256, 0, stream>>>(
        packed, edata, xws, dinv, b1, W2, ovfcnt, ovf, zp, N);

    int waves2 = (N + 15) / 16;
    agg2_final_kernel<<<(int)(((long long)waves2 * 64 + 255) / 256), 256, 0, stream>>>(
        packed, edata, zp, dinv, b2, ovfcnt, ovf, out, N);
}